// Round 9
// baseline (204.443 us; speedup 1.0000x reference)
//
#include <hip/hip_runtime.h>

typedef short short8  __attribute__((ext_vector_type(8)));
typedef short shortx4 __attribute__((ext_vector_type(4)));
typedef float floatx4 __attribute__((ext_vector_type(4)));
typedef unsigned short u16;

static __device__ __forceinline__ float bits2f(u16 s) {
    return __builtin_bit_cast(float, (unsigned)s << 16);
}
static __device__ __forceinline__ u16 f2bits(float f) {
    return __builtin_bit_cast(u16, (__bf16)f);   // RNE
}

#define SS 16

// ---- weight prepack ------------------------------------------------------
// wt0f [9][192][32] bf16 : ko<128 from W0 (gate 0-63, hidden 64-127),
//                          ko>=128 from R0 (residual).
// wt1  [9][128][64] bf16
__global__ void prep_kernel(const float* W0, const float* R0, const float* W1,
                            u16* wt0f, u16* wt1) {
    const int i = blockIdx.x * 256 + threadIdx.x;
    if (i < 55296) {
        const int t = i / 6144, r = i % 6144, ko = r >> 5, ci = r & 31;
        wt0f[i] = f2bits(ko < 128 ? W0[(ko * 32 + ci) * 9 + t]
                                  : R0[((ko - 128) * 32 + ci) * 9 + t]);
    } else if (i < 55296 + 73728) {
        const int j = i - 55296;
        const int t = j / 8192, r = j % 8192, ko = r >> 6, ci = r & 63;
        wt1[j] = f2bits(W1[(ko * 64 + ci) * 9 + t]);
    }
}

// ---- x (64,32,64,64) f32 NCHW -> xT (64,64,64,32) bf16 NHWC ---------------
__global__ void transpose_kernel(const float* __restrict__ x, u16* __restrict__ xT) {
    const int img = blockIdx.x >> 6, h = blockIdx.x & 63;
    const int gq = threadIdx.x & 3, w = threadIdx.x >> 2;
    short8 o;
#pragma unroll
    for (int k = 0; k < 8; ++k)
        o[k] = (short)f2bits(x[((size_t)img * 32 + gq * 8 + k) * 4096 + h * 64 + w]);
    ((short8*)xT)[((size_t)(img * 64 + h) * 64 + w) * 4 + gq] = o;
}

// ---- fused layer 0: conv3x3(32->192) + minGRU scan + residual -------------
// X = xT (64,64,64,32) bf16 NHWC. wt [9][192][32] bf16; bias = b0 (128) f32.
// x1out (64,64,64,64) bf16 NHWC; hlast (4,64,64,64) f32 NCHW.
// Tile = 2 rows x 16 cols; grid 512 = 2 blocks/CU.
// 2-TIMESTEP PIPELINE (r9): convs of s and s+1 are independent (only the
// per-thread GRU update is sequential), so each iteration stages TWO tiles
// into double-buffered LDS -> one barrier pair per 2 steps and 12 (vs 6)
// independent MFMA chains to hide dependent-MFMA latency.
__global__ __launch_bounds__(256, 2)
void fused_layer0_kernel(const u16* __restrict__ X, const u16* __restrict__ wt,
                         const float* __restrict__ bias,
                         u16* __restrict__ x1out, float* __restrict__ hlast) {
    __shared__ short8 lds[2][4 * 18 * 4];   // 2 x 4608 B

    const int tid = threadIdx.x;
    const int l   = tid & 63;
    const int wv  = tid >> 6;
    const int c16 = l & 15;
    const int q16 = l >> 4;

    const int bid = blockIdx.x;
    const int b   = bid >> 7;
    const int h0  = ((bid >> 2) & 31) * 2;
    const int w0  = (bid & 3) * 16;

    // ---- weights: 27 granules hoisted (9 taps x 3 groups) ----
    const short8* wtv = (const short8*)wt;
    short8 af[9][3];
#pragma unroll
    for (int t = 0; t < 9; ++t)
#pragma unroll
        for (int g = 0; g < 3; ++g)
            af[t][g] = wtv[(size_t)(t * 192 + (wv + g * 4) * 16 + c16) * 4 + q16];

    const floatx4 biasg = *(const floatx4*)(bias + wv * 16 + q16 * 4);
    const floatx4 biash = *(const floatx4*)(bias + 64 + wv * 16 + q16 * 4);

    // ---- staging geometry: 288 granules = 4r x 18c x 4q ----
    int ldsoff[2], goff[2];
    bool gval[2];
#pragma unroll
    for (int k = 0; k < 2; ++k) {
        const int idx = tid + k * 256;
        const int row = (idx >= 216) ? 3 : (idx >= 144) ? 2 : (idx >= 72) ? 1 : 0;
        const int rem = idx - row * 72;
        const int colrel = rem >> 2, q = rem & 3;
        const int hh = h0 - 1 + row;
        const int gc = w0 - 1 + colrel;
        ldsoff[k] = (row * 18 + colrel) * 4 + ((q + colrel) & 3);
        gval[k]   = (idx < 288) && ((unsigned)hh < 64u) && ((unsigned)gc < 64u);
        goff[k]   = (hh * 64 + gc) * 4 + q;
    }
    const bool k1 = (tid < 32);   // idx 256..287

    float hs[2][4];
#pragma unroll
    for (int m = 0; m < 2; ++m)
#pragma unroll
        for (int r = 0; r < 4; ++r) hs[m][r] = 0.5f;

    const short8* Xg = (const short8*)X;
    const short8 z8 = {0, 0, 0, 0, 0, 0, 0, 0};
    shortx4* x1v = (shortx4*)x1out;

    // prologue: load s=0 and s=1 into regs
    short8 vA0, vA1, vB0, vB1;
    {
        const short8* baseA = Xg + (size_t)(b * 16 + 0) * 16384;
        const short8* baseB = Xg + (size_t)(b * 16 + 1) * 16384;
        vA0 = gval[0] ? baseA[goff[0]] : z8;
        vA1 = gval[1] ? baseA[goff[1]] : z8;
        vB0 = gval[0] ? baseB[goff[0]] : z8;
        vB1 = gval[1] ? baseB[goff[1]] : z8;
    }

    for (int sp = 0; sp < SS / 2; ++sp) {
        const int s0 = sp * 2;

        lds[0][ldsoff[0]] = vA0;
        lds[1][ldsoff[0]] = vB0;
        if (k1) { lds[0][ldsoff[1]] = vA1; lds[1][ldsoff[1]] = vB1; }
        __syncthreads();

        // prefetch steps s0+2, s0+3 while computing s0, s0+1
        if (sp < SS / 2 - 1) {
            const short8* baseA = Xg + (size_t)(b * 16 + s0 + 2) * 16384;
            const short8* baseB = Xg + (size_t)(b * 16 + s0 + 3) * 16384;
            vA0 = gval[0] ? baseA[goff[0]] : z8;
            vA1 = gval[1] ? baseA[goff[1]] : z8;
            vB0 = gval[0] ? baseB[goff[0]] : z8;
            vB1 = gval[1] ? baseB[goff[1]] : z8;
        }

        // conv both steps: acc[st][g][m], g: 0=gate 1=hidden 2=res, m=row
        floatx4 acc[2][3][2];
#pragma unroll
        for (int st = 0; st < 2; ++st)
#pragma unroll
            for (int m = 0; m < 2; ++m) {
                acc[st][0][m] = biasg; acc[st][1][m] = biash;
                acc[st][2][m] = floatx4{0.0f, 0.0f, 0.0f, 0.0f};
            }
#pragma unroll
        for (int t = 0; t < 9; ++t) {
            const int dy = t / 3, dx = t - dy * 3;
#pragma unroll
            for (int m = 0; m < 2; ++m) {
                const int row = m + dy;
                const int lc  = c16 + dx;
                const int off = (row * 18 + lc) * 4 + ((q16 + lc) & 3);
                const short8 bfA = lds[0][off];
                const short8 bfB = lds[1][off];
#pragma unroll
                for (int g = 0; g < 3; ++g) {
                    acc[0][g][m] = __builtin_amdgcn_mfma_f32_16x16x32_bf16(
                        af[t][g], bfA, acc[0][g][m], 0, 0, 0);
                    acc[1][g][m] = __builtin_amdgcn_mfma_f32_16x16x32_bf16(
                        af[t][g], bfB, acc[1][g][m], 0, 0, 0);
                }
            }
        }

        // GRU updates (sequential in st) + residual + bf16 NHWC store of x1
#pragma unroll
        for (int st = 0; st < 2; ++st) {
#pragma unroll
            for (int m = 0; m < 2; ++m) {
                shortx4 ov;
#pragma unroll
                for (int r = 0; r < 4; ++r) {
                    const float g   = acc[st][0][m][r];
                    const float hid = acc[st][1][m][r];
                    const float zz  = 1.0f / (1.0f + __expf(-g));
                    const float gg  = (hid >= 0.0f) ? (hid + 0.5f)
                                                    : (1.0f / (1.0f + __expf(-hid)));
                    hs[m][r] = hs[m][r] + zz * (gg - hs[m][r]);
                    ov[r] = (short)f2bits(hs[m][r] + acc[st][2][m][r]);
                }
                const size_t px = ((size_t)(b * 16 + s0 + st) * 64 + (h0 + m)) * 64
                                  + w0 + c16;
                x1v[px * 16 + wv * 4 + q16] = ov;
            }
        }
        __syncthreads();   // all waves done reading lds before next ds_write
    }

    // hlast (4,64,64,64) f32 NCHW
    float* hp = hlast + ((size_t)(b * 64) + (wv * 16 + q16 * 4)) * 4096
                      + h0 * 64 + w0 + c16;
#pragma unroll
    for (int m = 0; m < 2; ++m)
#pragma unroll
        for (int r = 0; r < 4; ++r)
            hp[(size_t)r * 4096 + m * 64] = hs[m][r];
}

// ---- fused layer 1: conv3x3(64->128) + minGRU scan + residual -------------
// X = x1 (64,64,64,64) bf16 NHWC. wt [9][128][64] bf16; bias (128) f32.
// out (4,16,64,64,64) f32 NCHW; hlast (4,64,64,64) f32 NCHW.
// Tile = 2 rows x 16 cols; grid 512 = 2 blocks/CU. 2-timestep pipeline
// (see layer-0 note): double-buffered LDS, 8 independent MFMA chains,
// one barrier pair per 2 steps.
__global__ __launch_bounds__(256, 2)
void fused_layer1_kernel(const u16* __restrict__ X, const u16* __restrict__ wt,
                         const float* __restrict__ bias,
                         float* __restrict__ out, float* __restrict__ hlast) {
    __shared__ short8 lds[2][4 * 18 * 8];   // 2 x 9216 B

    const int tid = threadIdx.x;
    const int l   = tid & 63;
    const int wv  = tid >> 6;
    const int c16 = l & 15;
    const int q16 = l >> 4;

    const int bid = blockIdx.x;
    const int b   = bid >> 7;
    const int h0  = ((bid >> 2) & 31) * 2;
    const int w0  = (bid & 3) * 16;

    // ---- weights: 36 granules hoisted (2 ch-halves x 9 taps x 2 groups) ----
    const short8* wtv = (const short8*)wt;
    short8 af[2][9][2];
#pragma unroll
    for (int ch = 0; ch < 2; ++ch)
#pragma unroll
        for (int t = 0; t < 9; ++t)
#pragma unroll
            for (int g = 0; g < 2; ++g)
                af[ch][t][g] =
                    wtv[(size_t)(t * 128 + (wv + g * 4) * 16 + c16) * 8 + ch * 4 + q16];

    const floatx4 biasg = *(const floatx4*)(bias + wv * 16 + q16 * 4);
    const floatx4 biash = *(const floatx4*)(bias + 64 + wv * 16 + q16 * 4);

    // ---- staging geometry: 576 granules = 4r x 18c x 8q ----
    int ldsoff[3], goff[3];
    bool gval[3];
#pragma unroll
    for (int k = 0; k < 3; ++k) {
        const int idx = tid + k * 256;
        const int row = (idx >= 432) ? 3 : (idx >= 288) ? 2 : (idx >= 144) ? 1 : 0;
        const int rem = idx - row * 144;
        const int colrel = rem >> 3, q = rem & 7;
        const int hh = h0 - 1 + row;
        const int gc = w0 - 1 + colrel;
        ldsoff[k] = (row * 18 + colrel) * 8 + ((q + colrel) & 7);
        gval[k]   = (idx < 576) && ((unsigned)hh < 64u) && ((unsigned)gc < 64u);
        goff[k]   = (hh * 64 + gc) * 8 + q;
    }
    const bool k2 = (tid < 64);   // idx 512..575

    float hs[2][4];
#pragma unroll
    for (int m = 0; m < 2; ++m)
#pragma unroll
        for (int r = 0; r < 4; ++r) hs[m][r] = 0.5f;

    // out base: ch c=wv*16+q16*4, px (h0+m, w0+c16)
    float* op = out + ((size_t)(b * 16) * 64 + (wv * 16 + q16 * 4)) * 4096
                    + h0 * 64 + w0 + c16;

    const short8* Xg = (const short8*)X;
    const short8 z8 = {0, 0, 0, 0, 0, 0, 0, 0};

    // prologue: load s=0 and s=1 into regs
    short8 vA0, vA1, vA2, vB0, vB1, vB2;
    {
        const short8* baseA = Xg + (size_t)(b * 16 + 0) * 32768;
        const short8* baseB = Xg + (size_t)(b * 16 + 1) * 32768;
        vA0 = gval[0] ? baseA[goff[0]] : z8;
        vA1 = gval[1] ? baseA[goff[1]] : z8;
        vA2 = gval[2] ? baseA[goff[2]] : z8;
        vB0 = gval[0] ? baseB[goff[0]] : z8;
        vB1 = gval[1] ? baseB[goff[1]] : z8;
        vB2 = gval[2] ? baseB[goff[2]] : z8;
    }

    for (int sp = 0; sp < SS / 2; ++sp) {
        const int s0 = sp * 2;

        lds[0][ldsoff[0]] = vA0;
        lds[0][ldsoff[1]] = vA1;
        lds[1][ldsoff[0]] = vB0;
        lds[1][ldsoff[1]] = vB1;
        if (k2) { lds[0][ldsoff[2]] = vA2; lds[1][ldsoff[2]] = vB2; }
        __syncthreads();

        // prefetch steps s0+2, s0+3 while computing s0, s0+1
        if (sp < SS / 2 - 1) {
            const short8* baseA = Xg + (size_t)(b * 16 + s0 + 2) * 32768;
            const short8* baseB = Xg + (size_t)(b * 16 + s0 + 3) * 32768;
            vA0 = gval[0] ? baseA[goff[0]] : z8;
            vA1 = gval[1] ? baseA[goff[1]] : z8;
            vA2 = gval[2] ? baseA[goff[2]] : z8;
            vB0 = gval[0] ? baseB[goff[0]] : z8;
            vB1 = gval[1] ? baseB[goff[1]] : z8;
            vB2 = gval[2] ? baseB[goff[2]] : z8;
        }

        // conv both steps: acc[st][g][m], g: 0=gate 1=hidden, m=row
        floatx4 acc[2][2][2];
#pragma unroll
        for (int st = 0; st < 2; ++st)
#pragma unroll
            for (int m = 0; m < 2; ++m) {
                acc[st][0][m] = biasg; acc[st][1][m] = biash;
            }
#pragma unroll
        for (int ch = 0; ch < 2; ++ch)
#pragma unroll
            for (int t = 0; t < 9; ++t) {
                const int dy = t / 3, dx = t - dy * 3;
#pragma unroll
                for (int m = 0; m < 2; ++m) {
                    const int row = m + dy;
                    const int lc  = c16 + dx;
                    const int off = (row * 18 + lc) * 8 + ((ch * 4 + q16 + lc) & 7);
                    const short8 bfA = lds[0][off];
                    const short8 bfB = lds[1][off];
#pragma unroll
                    for (int g = 0; g < 2; ++g) {
                        acc[0][g][m] = __builtin_amdgcn_mfma_f32_16x16x32_bf16(
                            af[ch][t][g], bfA, acc[0][g][m], 0, 0, 0);
                        acc[1][g][m] = __builtin_amdgcn_mfma_f32_16x16x32_bf16(
                            af[ch][t][g], bfB, acc[1][g][m], 0, 0, 0);
                    }
                }
            }

        // GRU updates (sequential in st) + residual from LDS + f32 NCHW store
        const int qres = wv * 2 + (q16 >> 1);
#pragma unroll
        for (int st = 0; st < 2; ++st) {
            float* ops = op + (size_t)(s0 + st) * 262144;
#pragma unroll
            for (int m = 0; m < 2; ++m) {
                const int rowc = 1 + m;
                const int lcc  = 1 + c16;
                const shortx4 rr = *(const shortx4*)(
                    (const short*)&lds[st][(rowc * 18 + lcc) * 8 + ((qres + lcc) & 7)]
                    + (q16 & 1) * 4);
#pragma unroll
                for (int r = 0; r < 4; ++r) {
                    const float g   = acc[st][0][m][r];
                    const float hid = acc[st][1][m][r];
                    const float zz  = 1.0f / (1.0f + __expf(-g));
                    const float gg  = (hid >= 0.0f) ? (hid + 0.5f)
                                                    : (1.0f / (1.0f + __expf(-hid)));
                    hs[m][r] = hs[m][r] + zz * (gg - hs[m][r]);
                    const float o = hs[m][r] + bits2f((u16)rr[r]);
                    ops[(size_t)r * 4096 + m * 64] = o;
                }
            }
        }
        __syncthreads();   // all waves done reading lds before next ds_write
    }

    // hlast (4,64,64,64) f32 NCHW
    float* hp = hlast + ((size_t)(b * 64) + (wv * 16 + q16 * 4)) * 4096
                      + h0 * 64 + w0 + c16;
#pragma unroll
    for (int m = 0; m < 2; ++m)
#pragma unroll
        for (int r = 0; r < 4; ++r)
            hp[(size_t)r * 4096 + m * 64] = hs[m][r];
}

extern "C" void kernel_launch(void* const* d_in, const int* in_sizes, int n_in,
                              void* d_out, int out_size, void* d_ws, size_t ws_size,
                              hipStream_t stream) {
    const float* x  = (const float*)d_in[0];   // (4,16,32,64,64)
    const float* W0 = (const float*)d_in[1];   // (128,32,3,3)
    const float* b0 = (const float*)d_in[2];   // (128,)
    const float* R0 = (const float*)d_in[3];   // (64,32,3,3)
    const float* W1 = (const float*)d_in[4];   // (128,64,3,3)
    const float* b1 = (const float*)d_in[5];   // (128,)

    float* out = (float*)d_out;                 // (4,16,64,64,64) NCHW f32
    float* h0o = out + (size_t)16777216;
    float* h1o = h0o + (size_t)1048576;

    char* ws = (char*)d_ws;
    u16*   wt0f = (u16*)ws;                             // 110,592 B
    u16*   wt1  = (u16*)(ws + 110592);                  // 147,456 B -> ends 258,048
    u16*   xT   = (u16*)(ws + (size_t)(1  << 20));      // 16 MiB (NHWC bf16 input)
    u16*   x1   = (u16*)(ws + (size_t)(18 << 20));      // 32 MiB -> ends 50 MiB

    prep_kernel<<<504, 256, 0, stream>>>(W0, R0, W1, wt0f, wt1);
    transpose_kernel<<<4096, 256, 0, stream>>>(x, xT);

    // Layer 0: fused conv(32->192: gate/hidden/res) + GRU scan -> x1, h0o
    fused_layer0_kernel<<<512, 256, 0, stream>>>(xT, wt0f, b0, x1, h0o);

    // Layer 1: fused conv(64->128) + GRU scan + identity residual -> out, h1o
    fused_layer1_kernel<<<512, 256, 0, stream>>>(x1, wt1, b1, out, h1o);
}

// Round 10
// 191.347 us; speedup vs baseline: 1.0684x; 1.0684x over previous
//
#include <hip/hip_runtime.h>

typedef short short8  __attribute__((ext_vector_type(8)));
typedef short shortx4 __attribute__((ext_vector_type(4)));
typedef float floatx4 __attribute__((ext_vector_type(4)));
typedef unsigned short u16;

static __device__ __forceinline__ float bits2f(u16 s) {
    return __builtin_bit_cast(float, (unsigned)s << 16);
}
static __device__ __forceinline__ u16 f2bits(float f) {
    return __builtin_bit_cast(u16, (__bf16)f);   // RNE
}

#define SS 16

// ---- merged prepack + input transpose (one launch) ------------------------
// blocks [0,4096): x (64,32,64,64) f32 NCHW -> xT (64,64,64,32) bf16 NHWC
// blocks [4096,4600): wt0f [9][192][32] (W0 gate/hidden + R0 residual),
//                     wt1 [9][128][64]
__global__ void prep_transpose_kernel(const float* __restrict__ x, u16* __restrict__ xT,
                                      const float* W0, const float* R0, const float* W1,
                                      u16* wt0f, u16* wt1) {
    const int bid = blockIdx.x;
    if (bid < 4096) {
        const int img = bid >> 6, h = bid & 63;
        const int gq = threadIdx.x & 3, w = threadIdx.x >> 2;
        short8 o;
#pragma unroll
        for (int k = 0; k < 8; ++k)
            o[k] = (short)f2bits(x[((size_t)img * 32 + gq * 8 + k) * 4096 + h * 64 + w]);
        ((short8*)xT)[((size_t)(img * 64 + h) * 64 + w) * 4 + gq] = o;
        return;
    }
    const int i = (bid - 4096) * 256 + threadIdx.x;
    if (i < 55296) {
        const int t = i / 6144, r = i % 6144, ko = r >> 5, ci = r & 31;
        wt0f[i] = f2bits(ko < 128 ? W0[(ko * 32 + ci) * 9 + t]
                                  : R0[((ko - 128) * 32 + ci) * 9 + t]);
    } else if (i < 55296 + 73728) {
        const int j = i - 55296;
        const int t = j / 8192, r = j % 8192, ko = r >> 6, ci = r & 63;
        wt1[j] = f2bits(W1[(ko * 64 + ci) * 9 + t]);
    }
}

// ---- fused layer 0: conv3x3(32->192) + minGRU scan + residual -------------
// X = xT (64,64,64,32) bf16 NHWC. wt [9][192][32] bf16; bias = b0 (128) f32.
// x1out (64,64,64,64) bf16 NHWC; hlast (4,64,64,64) f32 NCHW.
// Tile = 2 rows x 16 cols; grid 512 = 2 blocks/CU.
// r10: double-buffered LDS, ONE barrier per step (r8 had two): write step
// s+1 into buf[cur^1] while computing step s from buf[cur]; safe because
// readers of cur^1 finished before the previous barrier. Per-step acc and
// store cadence identical to r8 (r9 showed batching stores 2-deep breaks
// sibling-block L2 write merging: WRITE 70->118MB).
__global__ __launch_bounds__(256, 2)
void fused_layer0_kernel(const u16* __restrict__ X, const u16* __restrict__ wt,
                         const float* __restrict__ bias,
                         u16* __restrict__ x1out, float* __restrict__ hlast) {
    __shared__ short8 lds[2][4 * 18 * 4];   // 2 x 4608 B

    const int tid = threadIdx.x;
    const int l   = tid & 63;
    const int wv  = tid >> 6;
    const int c16 = l & 15;
    const int q16 = l >> 4;

    const int bid = blockIdx.x;
    const int b   = bid >> 7;
    const int h0  = ((bid >> 2) & 31) * 2;
    const int w0  = (bid & 3) * 16;

    // ---- weights: 27 granules hoisted (9 taps x 3 groups) ----
    const short8* wtv = (const short8*)wt;
    short8 af[9][3];
#pragma unroll
    for (int t = 0; t < 9; ++t)
#pragma unroll
        for (int g = 0; g < 3; ++g)
            af[t][g] = wtv[(size_t)(t * 192 + (wv + g * 4) * 16 + c16) * 4 + q16];

    const floatx4 biasg = *(const floatx4*)(bias + wv * 16 + q16 * 4);
    const floatx4 biash = *(const floatx4*)(bias + 64 + wv * 16 + q16 * 4);

    // ---- staging geometry: 288 granules = 4r x 18c x 4q ----
    int ldsoff[2], goff[2];
    bool gval[2];
#pragma unroll
    for (int k = 0; k < 2; ++k) {
        const int idx = tid + k * 256;
        const int row = (idx >= 216) ? 3 : (idx >= 144) ? 2 : (idx >= 72) ? 1 : 0;
        const int rem = idx - row * 72;
        const int colrel = rem >> 2, q = rem & 3;
        const int hh = h0 - 1 + row;
        const int gc = w0 - 1 + colrel;
        ldsoff[k] = (row * 18 + colrel) * 4 + ((q + colrel) & 3);
        gval[k]   = (idx < 288) && ((unsigned)hh < 64u) && ((unsigned)gc < 64u);
        goff[k]   = (hh * 64 + gc) * 4 + q;
    }
    const bool k1 = (tid < 32);   // idx 256..287

    float hs[2][4];
#pragma unroll
    for (int m = 0; m < 2; ++m)
#pragma unroll
        for (int r = 0; r < 4; ++r) hs[m][r] = 0.5f;

    const short8* Xg = (const short8*)X;
    const short8 z8 = {0, 0, 0, 0, 0, 0, 0, 0};
    shortx4* x1v = (shortx4*)x1out;

    // prologue: stage s=0 into buf0; load s=1 into write-ahead regs
    short8 vW0, vW1;
    {
        const short8* base = Xg + (size_t)(b * 16) * 16384;
        vW0 = gval[0] ? base[goff[0]] : z8;
        vW1 = gval[1] ? base[goff[1]] : z8;
    }
    lds[0][ldsoff[0]] = vW0;
    if (k1) lds[0][ldsoff[1]] = vW1;
    {
        const short8* base = Xg + (size_t)(b * 16 + 1) * 16384;
        vW0 = gval[0] ? base[goff[0]] : z8;
        vW1 = gval[1] ? base[goff[1]] : z8;
    }
    __syncthreads();

#pragma unroll
    for (int s = 0; s < SS; ++s) {
        const int cur = s & 1;

        // write step s+1 into the other buffer (overlaps with compute below)
        if (s + 1 < SS) {
            lds[cur ^ 1][ldsoff[0]] = vW0;
            if (k1) lds[cur ^ 1][ldsoff[1]] = vW1;
        }
        // refill write-ahead regs with step s+2
        if (s + 2 < SS) {
            const short8* base = Xg + (size_t)(b * 16 + s + 2) * 16384;
            vW0 = gval[0] ? base[goff[0]] : z8;
            vW1 = gval[1] ? base[goff[1]] : z8;
        }

        // conv: acc[0]=gate, acc[1]=hidden, acc[2]=residual; m = out row
        floatx4 acc[3][2];
#pragma unroll
        for (int m = 0; m < 2; ++m) {
            acc[0][m] = biasg; acc[1][m] = biash;
            acc[2][m] = floatx4{0.0f, 0.0f, 0.0f, 0.0f};
        }
#pragma unroll
        for (int t = 0; t < 9; ++t) {
            const int dy = t / 3, dx = t - dy * 3;
#pragma unroll
            for (int m = 0; m < 2; ++m) {
                const int row = m + dy;
                const int lc  = c16 + dx;
                const short8 bf = lds[cur][(row * 18 + lc) * 4 + ((q16 + lc) & 3)];
#pragma unroll
                for (int g = 0; g < 3; ++g)
                    acc[g][m] = __builtin_amdgcn_mfma_f32_16x16x32_bf16(
                        af[t][g], bf, acc[g][m], 0, 0, 0);
            }
        }

        // GRU update + residual + bf16 NHWC store of x1 (same cadence as r8)
#pragma unroll
        for (int m = 0; m < 2; ++m) {
            shortx4 ov;
#pragma unroll
            for (int r = 0; r < 4; ++r) {
                const float g   = acc[0][m][r];
                const float hid = acc[1][m][r];
                const float zz  = 1.0f / (1.0f + __expf(-g));
                const float gg  = (hid >= 0.0f) ? (hid + 0.5f)
                                                : (1.0f / (1.0f + __expf(-hid)));
                hs[m][r] = hs[m][r] + zz * (gg - hs[m][r]);
                ov[r] = (short)f2bits(hs[m][r] + acc[2][m][r]);
            }
            const size_t px = ((size_t)(b * 16 + s) * 64 + (h0 + m)) * 64
                              + w0 + c16;
            x1v[px * 16 + wv * 4 + q16] = ov;
        }
        __syncthreads();   // single barrier per step
    }

    // hlast (4,64,64,64) f32 NCHW
    float* hp = hlast + ((size_t)(b * 64) + (wv * 16 + q16 * 4)) * 4096
                      + h0 * 64 + w0 + c16;
#pragma unroll
    for (int m = 0; m < 2; ++m)
#pragma unroll
        for (int r = 0; r < 4; ++r)
            hp[(size_t)r * 4096 + m * 64] = hs[m][r];
}

// ---- fused layer 1: conv3x3(64->128) + minGRU scan + residual -------------
// X = x1 (64,64,64,64) bf16 NHWC. wt [9][128][64] bf16; bias (128) f32.
// out (4,16,64,64,64) f32 NCHW; hlast (4,64,64,64) f32 NCHW.
// Tile = 2 rows x 16 cols; grid 512 = 2 blocks/CU. Double-buffered LDS,
// one barrier per step (see layer-0 note); r8 per-step acc/store cadence.
__global__ __launch_bounds__(256, 2)
void fused_layer1_kernel(const u16* __restrict__ X, const u16* __restrict__ wt,
                         const float* __restrict__ bias,
                         float* __restrict__ out, float* __restrict__ hlast) {
    __shared__ short8 lds[2][4 * 18 * 8];   // 2 x 9216 B

    const int tid = threadIdx.x;
    const int l   = tid & 63;
    const int wv  = tid >> 6;
    const int c16 = l & 15;
    const int q16 = l >> 4;

    const int bid = blockIdx.x;
    const int b   = bid >> 7;
    const int h0  = ((bid >> 2) & 31) * 2;
    const int w0  = (bid & 3) * 16;

    // ---- weights: 36 granules hoisted (2 ch-halves x 9 taps x 2 groups) ----
    const short8* wtv = (const short8*)wt;
    short8 af[2][9][2];
#pragma unroll
    for (int ch = 0; ch < 2; ++ch)
#pragma unroll
        for (int t = 0; t < 9; ++t)
#pragma unroll
            for (int g = 0; g < 2; ++g)
                af[ch][t][g] =
                    wtv[(size_t)(t * 128 + (wv + g * 4) * 16 + c16) * 8 + ch * 4 + q16];

    const floatx4 biasg = *(const floatx4*)(bias + wv * 16 + q16 * 4);
    const floatx4 biash = *(const floatx4*)(bias + 64 + wv * 16 + q16 * 4);

    // ---- staging geometry: 576 granules = 4r x 18c x 8q ----
    int ldsoff[3], goff[3];
    bool gval[3];
#pragma unroll
    for (int k = 0; k < 3; ++k) {
        const int idx = tid + k * 256;
        const int row = (idx >= 432) ? 3 : (idx >= 288) ? 2 : (idx >= 144) ? 1 : 0;
        const int rem = idx - row * 144;
        const int colrel = rem >> 3, q = rem & 7;
        const int hh = h0 - 1 + row;
        const int gc = w0 - 1 + colrel;
        ldsoff[k] = (row * 18 + colrel) * 8 + ((q + colrel) & 7);
        gval[k]   = (idx < 576) && ((unsigned)hh < 64u) && ((unsigned)gc < 64u);
        goff[k]   = (hh * 64 + gc) * 8 + q;
    }
    const bool k2 = (tid < 64);   // idx 512..575

    float hs[2][4];
#pragma unroll
    for (int m = 0; m < 2; ++m)
#pragma unroll
        for (int r = 0; r < 4; ++r) hs[m][r] = 0.5f;

    // out base: ch c=wv*16+q16*4, px (h0+m, w0+c16)
    float* op = out + ((size_t)(b * 16) * 64 + (wv * 16 + q16 * 4)) * 4096
                    + h0 * 64 + w0 + c16;

    const short8* Xg = (const short8*)X;
    const short8 z8 = {0, 0, 0, 0, 0, 0, 0, 0};

    // prologue: stage s=0 into buf0; load s=1 into write-ahead regs
    short8 vW0, vW1, vW2;
    {
        const short8* base = Xg + (size_t)(b * 16) * 32768;
        vW0 = gval[0] ? base[goff[0]] : z8;
        vW1 = gval[1] ? base[goff[1]] : z8;
        vW2 = gval[2] ? base[goff[2]] : z8;
    }
    lds[0][ldsoff[0]] = vW0;
    lds[0][ldsoff[1]] = vW1;
    if (k2) lds[0][ldsoff[2]] = vW2;
    {
        const short8* base = Xg + (size_t)(b * 16 + 1) * 32768;
        vW0 = gval[0] ? base[goff[0]] : z8;
        vW1 = gval[1] ? base[goff[1]] : z8;
        vW2 = gval[2] ? base[goff[2]] : z8;
    }
    __syncthreads();

#pragma unroll
    for (int s = 0; s < SS; ++s) {
        const int cur = s & 1;

        // write step s+1 into the other buffer (overlaps with compute below)
        if (s + 1 < SS) {
            lds[cur ^ 1][ldsoff[0]] = vW0;
            lds[cur ^ 1][ldsoff[1]] = vW1;
            if (k2) lds[cur ^ 1][ldsoff[2]] = vW2;
        }
        // refill write-ahead regs with step s+2
        if (s + 2 < SS) {
            const short8* base = Xg + (size_t)(b * 16 + s + 2) * 32768;
            vW0 = gval[0] ? base[goff[0]] : z8;
            vW1 = gval[1] ? base[goff[1]] : z8;
            vW2 = gval[2] ? base[goff[2]] : z8;
        }

        // conv: acc[0]=gate, acc[1]=hidden; m = out row
        floatx4 acc[2][2];
#pragma unroll
        for (int m = 0; m < 2; ++m) { acc[0][m] = biasg; acc[1][m] = biash; }
#pragma unroll
        for (int ch = 0; ch < 2; ++ch)
#pragma unroll
            for (int t = 0; t < 9; ++t) {
                const int dy = t / 3, dx = t - dy * 3;
#pragma unroll
                for (int m = 0; m < 2; ++m) {
                    const int row = m + dy;
                    const int lc  = c16 + dx;
                    const short8 bf =
                        lds[cur][(row * 18 + lc) * 8 + ((ch * 4 + q16 + lc) & 7)];
                    acc[0][m] = __builtin_amdgcn_mfma_f32_16x16x32_bf16(
                        af[ch][t][0], bf, acc[0][m], 0, 0, 0);
                    acc[1][m] = __builtin_amdgcn_mfma_f32_16x16x32_bf16(
                        af[ch][t][1], bf, acc[1][m], 0, 0, 0);
                }
            }

        // GRU update + residual (from staged LDS) + direct NCHW f32 store
        float* ops = op + (size_t)s * 262144;   // 64*4096 floats per timestep
        const int qres = wv * 2 + (q16 >> 1);
#pragma unroll
        for (int m = 0; m < 2; ++m) {
            const int rowc = 1 + m;
            const int lcc  = 1 + c16;
            const shortx4 rr = *(const shortx4*)(
                (const short*)&lds[cur][(rowc * 18 + lcc) * 8 + ((qres + lcc) & 7)]
                + (q16 & 1) * 4);
#pragma unroll
            for (int r = 0; r < 4; ++r) {
                const float g   = acc[0][m][r];
                const float hid = acc[1][m][r];
                const float zz  = 1.0f / (1.0f + __expf(-g));
                const float gg  = (hid >= 0.0f) ? (hid + 0.5f)
                                                : (1.0f / (1.0f + __expf(-hid)));
                hs[m][r] = hs[m][r] + zz * (gg - hs[m][r]);
                const float o = hs[m][r] + bits2f((u16)rr[r]);
                ops[(size_t)r * 4096 + m * 64] = o;
            }
        }
        __syncthreads();   // single barrier per step
    }

    // hlast (4,64,64,64) f32 NCHW
    float* hp = hlast + ((size_t)(b * 64) + (wv * 16 + q16 * 4)) * 4096
                      + h0 * 64 + w0 + c16;
#pragma unroll
    for (int m = 0; m < 2; ++m)
#pragma unroll
        for (int r = 0; r < 4; ++r)
            hp[(size_t)r * 4096 + m * 64] = hs[m][r];
}

extern "C" void kernel_launch(void* const* d_in, const int* in_sizes, int n_in,
                              void* d_out, int out_size, void* d_ws, size_t ws_size,
                              hipStream_t stream) {
    const float* x  = (const float*)d_in[0];   // (4,16,32,64,64)
    const float* W0 = (const float*)d_in[1];   // (128,32,3,3)
    const float* b0 = (const float*)d_in[2];   // (128,)
    const float* R0 = (const float*)d_in[3];   // (64,32,3,3)
    const float* W1 = (const float*)d_in[4];   // (128,64,3,3)
    const float* b1 = (const float*)d_in[5];   // (128,)

    float* out = (float*)d_out;                 // (4,16,64,64,64) NCHW f32
    float* h0o = out + (size_t)16777216;
    float* h1o = h0o + (size_t)1048576;

    char* ws = (char*)d_ws;
    u16*   wt0f = (u16*)ws;                             // 110,592 B
    u16*   wt1  = (u16*)(ws + 110592);                  // 147,456 B -> ends 258,048
    u16*   xT   = (u16*)(ws + (size_t)(1  << 20));      // 16 MiB (NHWC bf16 input)
    u16*   x1   = (u16*)(ws + (size_t)(18 << 20));      // 32 MiB -> ends 50 MiB

    // merged prepack + transpose: one launch
    prep_transpose_kernel<<<4600, 256, 0, stream>>>(x, xT, W0, R0, W1, wt0f, wt1);

    // Layer 0: fused conv(32->192: gate/hidden/res) + GRU scan -> x1, h0o
    fused_layer0_kernel<<<512, 256, 0, stream>>>(xT, wt0f, b0, x1, h0o);

    // Layer 1: fused conv(64->128) + GRU scan + identity residual -> out, h1o
    fused_layer1_kernel<<<512, 256, 0, stream>>>(x1, wt1, b1, out, h1o);
}